// Round 10
// baseline (374.333 us; speedup 1.0000x reference)
//
#include <hip/hip_runtime.h>
#include <cstdint>
#include <cstddef>

#define BATCH  4
#define RUNITS 128
#define MM     5
#define SEG    128            // ushorts per b-segment (c 0..127)
#define US     512            // ushorts per node row-level = 4*SEG (1024 B)
#define KB     672            // GEMM K: 20 steps (m*128+c) + 1 tail step (c==128, m=0..4)

typedef unsigned int  uint32;
typedef unsigned short ushort16;
typedef __attribute__((ext_vector_type(8))) short short8;
typedef __attribute__((ext_vector_type(4))) float f32x4;

__device__ inline float bflo(uint32 u){ return __uint_as_float(u << 16); }
__device__ inline float bfhi(uint32 u){ return __uint_as_float(u & 0xFFFF0000u); }
__device__ inline ushort16 f2bf(float f){
  uint32 u = __float_as_uint(f);
  return (ushort16)((u + 0x7FFFu + ((u >> 16) & 1u)) >> 16);
}
__device__ inline float bf2f(ushort16 v){ return __uint_as_float(((uint32)v) << 16); }
__device__ inline int sw4(int r){ return (r ^ (r >> 2)) & 3; }

// ---------------- graph prep ----------------

__global__ void k_zero_i(int* p, int n) {
  int i = blockIdx.x*blockDim.x + threadIdx.x;
  if (i < n) p[i] = 0;
}

__global__ void k_deg_cnt(const int* __restrict__ src, const int* __restrict__ dst,
                          const float* __restrict__ w, int E,
                          float* deg_out, float* deg_in, int* cnt_f, int* cnt_b) {
  int e = blockIdx.x*blockDim.x + threadIdx.x;
  if (e >= E) return;
  int s = src[e], d = dst[e]; float we = w[e];
  atomicAdd(&deg_out[s], we);
  atomicAdd(&deg_in[d], we);
  atomicAdd(&cnt_f[s], 1);
  atomicAdd(&cnt_b[d], 1);
}

__global__ __launch_bounds__(256) void k_scansum(
    const int* __restrict__ cnt_f, const int* __restrict__ cnt_b, int* bsum, int n) {
  const int* cnt = blockIdx.y ? cnt_b : cnt_f;
  int tid = threadIdx.x, lane = tid & 63, wv = tid >> 6;
  int i = blockIdx.x*256 + tid;
  int v = (i < n) ? cnt[i] : 0;
  #pragma unroll
  for (int d = 32; d > 0; d >>= 1) v += __shfl_down(v, d);
  __shared__ int sm[4];
  if (lane == 0) sm[wv] = v;
  __syncthreads();
  if (tid == 0) bsum[blockIdx.y*40 + blockIdx.x] = sm[0]+sm[1]+sm[2]+sm[3];
}

__global__ __launch_bounds__(64) void k_scanmid(
    const int* bsum, int* bofs, int* ptrF, int* ptrB, int n, int nb) {
  int lane = threadIdx.x;
  for (int a = 0; a < 2; ++a) {
    int v = (lane < nb) ? bsum[a*nb + lane] : 0;
    int x = v;
    #pragma unroll
    for (int d = 1; d < 64; d <<= 1) { int t = __shfl_up(x, d); if (lane >= d) x += t; }
    if (lane < nb) bofs[a*nb + lane] = x - v;
    if (lane == nb - 1) { if (a) ptrB[n] = x; else ptrF[n] = x; }
  }
}

__global__ __launch_bounds__(256) void k_scanapply(
    const int* __restrict__ cnt_f, const int* __restrict__ cnt_b, const int* __restrict__ bofs,
    int* ptrF, int* curF, int* ptrB, int* curB, int n) {
  int a = blockIdx.y;
  const int* cnt = a ? cnt_b : cnt_f;
  int* ptr = a ? ptrB : ptrF;
  int* cur = a ? curB : curF;
  int tid = threadIdx.x, lane = tid & 63, wv = tid >> 6;
  int i = blockIdx.x*256 + tid;
  int v = (i < n) ? cnt[i] : 0;
  int x = v;
  #pragma unroll
  for (int d = 1; d < 64; d <<= 1) { int t = __shfl_up(x, d); if (lane >= d) x += t; }
  __shared__ int ws[4];
  __shared__ int wo[4];
  if (lane == 63) ws[wv] = x;
  __syncthreads();
  if (tid == 0) { int s = 0; for (int k = 0; k < 4; ++k) { wo[k] = s; s += ws[k]; } }
  __syncthreads();
  int excl = x - v + wo[wv] + bofs[a*40 + blockIdx.x];
  if (i < n) { ptr[i] = excl; cur[i] = excl; }
}

__global__ void k_fill(const int* __restrict__ src, const int* __restrict__ dst,
                       const float* __restrict__ w, int E,
                       const float* __restrict__ deg_out, const float* __restrict__ deg_in,
                       int* cur_f, int* cur_b,
                       int* col_f, float* val_f, int* col_b, float* val_b) {
  int e = blockIdx.x*blockDim.x + threadIdx.x;
  if (e >= E) return;
  int s = src[e], d = dst[e]; float we = w[e];
  int pf = atomicAdd(&cur_f[s], 1);
  col_f[pf] = d; val_f[pf] = we / deg_out[s];
  int pb = atomicAdd(&cur_b[d], 1);
  col_b[pb] = s; val_b[pb] = we / deg_in[d];
}

// ---------------- weight pack ----------------

__global__ void k_packw(const float* __restrict__ W, ushort16* __restrict__ Bt, int ncol) {
  int idx = blockIdx.x*blockDim.x + threadIdx.x;
  int total = ncol * KB;
  if (idx >= total) return;
  int o = idx / KB, k = idx - o*KB;
  float v = 0.f;
  if (k < 640) {
    int m = k >> 7, c = k & 127;
    v = W[(size_t)(c*MM + m)*ncol + o];
  } else if (k < 645) {
    v = W[(size_t)k*ncol + o];
  }
  Bt[idx] = f2bf(v);
}

// ---------------- build x0 (gconv1 only): level0 + xtail phase-0 slot 0 ----------------
// xtail layout: [n][b][16 slots]; phase 0 = gconv1 (slots 0..4), phase 1 = gconv2 (8..12)

__global__ __launch_bounds__(256) void k_build_x0(
    const float* __restrict__ inp, const float* __restrict__ hf,
    ushort16* __restrict__ x0, ushort16* __restrict__ xtail, int N) {
  int wv = threadIdx.x >> 6, lane = threadIdx.x & 63;
  int n = blockIdx.x*4 + wv;
  if (n >= N) return;
  int b = lane >> 4, ch = lane & 15;
  size_t r = (size_t)b*N + n;
  size_t hbase = r*RUNITS;
  short8 pk;
  if (ch == 0) {
    pk[0] = (short)f2bf(inp[r]);
    #pragma unroll
    for (int s = 1; s < 8; ++s) pk[s] = (short)f2bf(hf[hbase + s - 1]);
  } else {
    int c0 = ch*8 - 1;
    #pragma unroll
    for (int s = 0; s < 8; ++s) pk[s] = (short)f2bf(hf[hbase + c0 + s]);
  }
  *(short8*)&x0[(size_t)n*US + b*SEG + ch*8] = pk;
  if (ch == 15) {
    xtail[((size_t)n*4 + b)*16 + 0] = f2bf(hf[hbase + 127]);
  }
}

// ---------------- L2-resident quartered dual SPMM ----------------
// bid&7 -> (jb = &1, q = >>1): each XCD gathers one N x 256B quarter (2.56MB, L2-fit).
// Wave: 4 nodes (lane>>4) x 16 chunks (lane&15); all 64 lanes active.
// Loop trip = wave-max degree; inactive lanes predicated (v=0).
// Lane c==0 of each group carries the c==128 tail for batch q.

template<bool HY>
__global__ __launch_bounds__(256) void k_spmm2(
    const int* __restrict__ ptrF, const int* __restrict__ colF, const float* __restrict__ valF,
    const int* __restrict__ ptrB, const int* __restrict__ colB, const float* __restrict__ valB,
    const ushort16* __restrict__ xinF, const ushort16* __restrict__ xinB,
    ushort16* __restrict__ xoutF, ushort16* __restrict__ xoutB,
    const ushort16* __restrict__ Y0, ushort16* __restrict__ xtail,
    int tinF, int tinB, int toutF, int toutB, int tz,
    int N, float alpha, float beta) {
  int bid = blockIdx.x;
  int xcd = bid & 7;
  int jb = xcd & 1, q = xcd >> 1;
  int wv = threadIdx.x >> 6, lane = threadIdx.x & 63;
  int g = lane >> 4, c = lane & 15;
  int n = (bid >> 3)*16 + wv*4 + g;
  const int* ptr = jb ? ptrB : ptrF;
  const int* col = jb ? colB : colF;
  const float* val = jb ? valB : valF;
  const ushort16* X = jb ? xinB : xinF;
  ushort16* out = jb ? xoutB : xoutF;
  int tin = jb ? tinB : tinF;
  int tout = jb ? toutB : toutF;

  bool nok = n < N;
  int s = 0, cnt = 0;
  if (nok) { s = ptr[n]; cnt = ptr[n+1] - s; }
  int mcnt = cnt;
  mcnt = max(mcnt, __shfl_xor(mcnt, 16));
  mcnt = max(mcnt, __shfl_xor(mcnt, 32));

  size_t qoff = (size_t)q*SEG + c*8;
  bool tq = (c == 0);
  float a[8] = {0.f,0.f,0.f,0.f,0.f,0.f,0.f,0.f};
  float at = 0.f;
  #pragma unroll 4
  for (int i = 0; i < mcnt; ++i) {
    bool act = i < cnt;
    int idx = act ? s + i : 0;
    int cl = col[idx];
    float v = act ? val[idx] : 0.f;
    uint4 u = *(const uint4*)(X + (size_t)cl*US + qoff);
    a[0] += v*bflo(u.x); a[1] += v*bfhi(u.x);
    a[2] += v*bflo(u.y); a[3] += v*bfhi(u.y);
    a[4] += v*bflo(u.z); a[5] += v*bfhi(u.z);
    a[6] += v*bflo(u.w); a[7] += v*bfhi(u.w);
    if (tq) at += v * bf2f(xtail[((size_t)cl*4 + q)*16 + tin]);
  }
  if (!nok) return;

  size_t ob = (size_t)n*US + qoff;
  float r[8];
  if (HY) {
    uint4 y = *(const uint4*)(Y0 + ob);
    r[0] = alpha*a[0] + beta*bflo(y.x); r[1] = alpha*a[1] + beta*bfhi(y.x);
    r[2] = alpha*a[2] + beta*bflo(y.y); r[3] = alpha*a[3] + beta*bfhi(y.y);
    r[4] = alpha*a[4] + beta*bflo(y.z); r[5] = alpha*a[5] + beta*bfhi(y.z);
    r[6] = alpha*a[6] + beta*bflo(y.w); r[7] = alpha*a[7] + beta*bfhi(y.w);
  } else {
    #pragma unroll
    for (int k = 0; k < 8; ++k) r[k] = alpha*a[k];
  }
  short8 pk;
  #pragma unroll
  for (int k = 0; k < 8; ++k) pk[k] = (short)f2bf(r[k]);
  *(short8*)&out[ob] = pk;
  if (tq) {
    float rt = alpha*at;
    if (HY) rt += beta * bf2f(xtail[((size_t)n*4 + q)*16 + tz]);
    xtail[((size_t)n*4 + q)*16 + tout] = f2bf(rt);
  }
}

// ---------------- unified MFMA GEMM ----------------
// 256 thr, 4 waves (2x2), wave-tile (TM/2) x 64, K = 21 steps, LDS dbuf, XOR swizzle.
// MODE 0 (gates, grid.y=2 panels): sigmoid; by=0 -> writes r*hx DIRECTLY into x5
//   (gconv2 level-0 layout, c=o+1; c0 from inputs; c128 -> xtail slot 8); by=1 -> ub.
// MODE 1 (cand, A level m=0 comes from x5): tanh + GRU combine + fused projection.

template<int TM, int MODE>
__global__ __launch_bounds__(256, 5) void k_gemm(
    const ushort16* __restrict__ xall, const ushort16* __restrict__ xtail,
    const ushort16* __restrict__ Bt, const float* __restrict__ bias,
    const float* __restrict__ hx, const float* __restrict__ inp,
    ushort16* __restrict__ x5w, ushort16* __restrict__ xtw,
    ushort16* __restrict__ ub, float* __restrict__ outh,
    float* __restrict__ outy, const float* __restrict__ wpj,
    int N, int BN) {
  constexpr int NI = TM / 32;
  __shared__ __align__(16) ushort16 As[2][TM*32];
  __shared__ __align__(16) ushort16 Bs[2][128*32];
  int tid = threadIdx.x, lane = tid & 63, wv = tid >> 6;
  int wm = wv >> 1, wn = wv & 1;
  int fr = lane & 15, g = lane >> 4;
  int R0 = blockIdx.x*TM, by = blockIdx.y;
  const size_t mstride = (size_t)N*US;
  const size_t l0off = (MODE == 1) ? (size_t)5*mstride : 0;

  int r = tid >> 2, p = tid & 3;
  bool aact = (TM == 64) || (tid < TM*4);
  int sa = p ^ sw4(r);
  int gr = R0 + r; if (gr >= BN) gr = BN - 1;
  int bA = gr / N, nA = gr - bA*N;
  const ushort16* aBase = xall + (size_t)nA*US + bA*SEG;
  const ushort16* tBase = xtail + ((size_t)nA*4 + bA)*16 + (MODE == 1 ? 8 : 0);
  int aofs = r*32 + (p << 3);

  int cB = tid >> 1, u = tid & 1;
  int p0 = 2*u, p1 = 2*u + 1;
  int sb0 = p0 ^ sw4(cB), sb1 = p1 ^ sw4(cB);
  const ushort16* bBase = Bt + (size_t)(by*128 + cB)*KB;
  int bofs0 = cB*32 + (p0 << 3), bofs1 = cB*32 + (p1 << 3);

  f32x4 acc[NI][4];
  #pragma unroll
  for (int i = 0; i < NI; ++i)
    #pragma unroll
    for (int j = 0; j < 4; ++j) acc[i][j] = (f32x4){0.f,0.f,0.f,0.f};

  uint4 ra, rb0, rb1;
  if (aact) ra = *(const uint4*)(aBase + l0off + sa*8);
  rb0 = *(const uint4*)(bBase + sb0*8);
  rb1 = *(const uint4*)(bBase + sb1*8);

  int buf = 0;
  for (int s = 0; s < 21; ++s) {
    if (aact) *(uint4*)&As[buf][aofs] = ra;
    *(uint4*)&Bs[buf][bofs0] = rb0;
    *(uint4*)&Bs[buf][bofs1] = rb1;
    __syncthreads();
    if (s < 20) {
      int s1 = s + 1;
      if (aact) {
        if (s1 < 20) {
          int qk = 4*s1 + sa;
          int m = qk >> 4;
          size_t mo = (m == 0) ? l0off : (size_t)m*mstride;
          ra = *(const uint4*)(aBase + mo + (qk & 15)*8);
        } else if (sa == 0) {
          ra = *(const uint4*)tBase;   // 5 real slots; pads killed by B zeros
        }
      }
      rb0 = *(const uint4*)(bBase + (4*s1 + sb0)*8);
      rb1 = *(const uint4*)(bBase + (4*s1 + sb1)*8);
    }
    short8 af[NI], bfv[4];
    #pragma unroll
    for (int i = 0; i < NI; ++i) {
      int rr = wm*(NI*16) + i*16 + fr;
      af[i] = *(const short8*)&As[buf][rr*32 + ((g ^ sw4(rr)) << 3)];
    }
    #pragma unroll
    for (int j = 0; j < 4; ++j) {
      int cc = wn*64 + j*16 + fr;
      bfv[j] = *(const short8*)&Bs[buf][cc*32 + ((g ^ sw4(cc)) << 3)];
    }
    #pragma unroll
    for (int i = 0; i < NI; ++i)
      #pragma unroll
      for (int j = 0; j < 4; ++j)
        acc[i][j] = __builtin_amdgcn_mfma_f32_16x16x32_bf16(af[i], bfv[j], acc[i][j], 0, 0, 0);
    buf ^= 1;
  }

  #pragma unroll
  for (int i = 0; i < NI; ++i) {
    #pragma unroll
    for (int q2 = 0; q2 < 4; ++q2) {
      int row = R0 + wm*(NI*16) + i*16 + g*4 + q2;
      bool rok = row < BN;
      if (MODE == 0) {
        if (!rok) continue;
        int b2 = row / N, n2 = row - b2*N;
        #pragma unroll
        for (int j = 0; j < 4; ++j) {
          int o = wn*64 + j*16 + fr;
          float gv = acc[i][j][q2] + bias[by*128 + o];
          float sg = 1.f/(1.f + expf(-gv));
          if (by == 0) {
            float rv = sg * hx[(size_t)row*RUNITS + o];
            if (o < 127)
              x5w[(size_t)n2*US + b2*SEG + o + 1] = f2bf(rv);
            else
              xtw[((size_t)n2*4 + b2)*16 + 8] = f2bf(rv);
            if (o == 0)
              x5w[(size_t)n2*US + b2*SEG] = f2bf(inp[row]);
          } else {
            ub[(size_t)row*RUNITS + o] = f2bf(sg);
          }
        }
      } else {
        float pj = 0.f;
        #pragma unroll
        for (int j = 0; j < 4; ++j) {
          int o = wn*64 + j*16 + fr;
          float gv = acc[i][j][q2] + bias[o];
          float cv = tanhf(gv);
          if (rok) {
            float uu = bf2f(ub[(size_t)row*RUNITS + o]);
            float hh = hx[(size_t)row*RUNITS + o];
            float nh = uu*hh + (1.f - uu)*cv;
            outh[(size_t)row*RUNITS + o] = nh;
            pj += nh * wpj[o];
          }
        }
        #pragma unroll
        for (int d = 1; d < 16; d <<= 1) pj += __shfl_xor(pj, d);
        if (rok && fr == 0) atomicAdd(&outy[row], pj);
      }
    }
  }
}

__global__ void k_inity(float* y, const float* bp, int n) {
  int i = blockIdx.x*blockDim.x + threadIdx.x;
  if (i < n) y[i] = bp[0];
}

// ---------------- launcher ----------------

extern "C" void kernel_launch(void* const* d_in, const int* in_sizes, int n_in,
                              void* d_out, int out_size, void* d_ws, size_t ws_size,
                              hipStream_t stream) {
  const float* inputs = (const float*)d_in[0];
  const float* hidden = (const float*)d_in[1];
  const int*   esrc   = (const int*)d_in[2];
  const int*   edst   = (const int*)d_in[3];
  const float* ew     = (const float*)d_in[4];
  const float* Wg     = (const float*)d_in[5];
  const float* bg     = (const float*)d_in[6];
  const float* Wc     = (const float*)d_in[7];
  const float* bc     = (const float*)d_in[8];
  const float* Wpj    = (const float*)d_in[9];
  const float* bpj    = (const float*)d_in[10];

  const int N  = in_sizes[0] / BATCH;
  const int E  = in_sizes[2];
  const int BN = BATCH * N;

  char* p = (char*)d_ws;
  auto alloc = [&](size_t bytes) -> void* {
    void* r = (void*)p;
    p += (bytes + 255) & ~(size_t)255;
    return r;
  };

  float* deg_out = (float*)alloc((size_t)4*N*sizeof(float));
  float* deg_in  = deg_out + N;
  int*   cnt_f   = (int*)(deg_out + 2*(size_t)N);
  int*   cnt_b   = cnt_f + N;
  int*   ptr_f   = (int*)alloc((size_t)(N+1)*sizeof(int));
  int*   ptr_b   = (int*)alloc((size_t)(N+1)*sizeof(int));
  int*   cur_f   = (int*)alloc((size_t)N*sizeof(int));
  int*   cur_b   = (int*)alloc((size_t)N*sizeof(int));
  int*   col_f   = (int*)alloc((size_t)E*sizeof(int));
  int*   col_b   = (int*)alloc((size_t)E*sizeof(int));
  float* val_f   = (float*)alloc((size_t)E*sizeof(float));
  float* val_b   = (float*)alloc((size_t)E*sizeof(float));
  int*   bsum    = (int*)alloc(80*sizeof(int));
  int*   bofs    = (int*)alloc(80*sizeof(int));
  ushort16* WtG  = (ushort16*)alloc((size_t)2*RUNITS*KB*sizeof(ushort16));
  ushort16* WtC  = (ushort16*)alloc((size_t)RUNITS*KB*sizeof(ushort16));
  ushort16* xall = (ushort16*)alloc((size_t)6*N*US*sizeof(ushort16));   // levels 0..4 + x5
  ushort16* xtail= (ushort16*)alloc((size_t)N*4*16*sizeof(ushort16));
  ushort16* ub   = (ushort16*)alloc((size_t)BN*RUNITS*sizeof(ushort16));

  float* out_y = (float*)d_out;
  float* out_h = out_y + BN;

  ushort16* x0 = xall;
  ushort16* x1 = xall + (size_t)1*N*US;
  ushort16* x2 = xall + (size_t)2*N*US;
  ushort16* x3 = xall + (size_t)3*N*US;
  ushort16* x4 = xall + (size_t)4*N*US;
  ushort16* x5 = xall + (size_t)5*N*US;

  const int TB = 256;
  int nb = (N + 255)/256;
  k_zero_i<<<(4*N+TB-1)/TB, TB, 0, stream>>>((int*)deg_out, 4*N);
  k_deg_cnt<<<(E+TB-1)/TB, TB, 0, stream>>>(esrc, edst, ew, E, deg_out, deg_in, cnt_f, cnt_b);
  k_scansum<<<dim3(nb,2), TB, 0, stream>>>(cnt_f, cnt_b, bsum, N);
  k_scanmid<<<1, 64, 0, stream>>>(bsum, bofs, ptr_f, ptr_b, N, nb);
  k_scanapply<<<dim3(nb,2), TB, 0, stream>>>(cnt_f, cnt_b, bofs, ptr_f, cur_f, ptr_b, cur_b, N);
  k_fill<<<(E+TB-1)/TB, TB, 0, stream>>>(esrc, edst, ew, E, deg_out, deg_in,
                                         cur_f, cur_b, col_f, val_f, col_b, val_b);
  k_packw<<<(2*RUNITS*KB+TB-1)/TB, TB, 0, stream>>>(Wg, WtG, 2*RUNITS);
  k_packw<<<(RUNITS*KB+TB-1)/TB, TB, 0, stream>>>(Wc, WtC, RUNITS);
  k_inity<<<(BN+TB-1)/TB, TB, 0, stream>>>(out_y, bpj, BN);

  int sgrid = (N + 3) / 4;
  int qgrid = 8 * ((N + 15) / 16);
  int gx64 = (BN + 63) / 64;
  int gx32 = (BN + 31) / 32;

  // ---- gates gconv ----
  k_build_x0<<<sgrid, TB, 0, stream>>>(inputs, hidden, x0, xtail, N);
  k_spmm2<false><<<qgrid, TB, 0, stream>>>(ptr_f, col_f, val_f, ptr_b, col_b, val_b,
                                           x0, x0, x1, x3, x0, xtail,
                                           0, 0, 1, 3, 0, N, 1.f, 0.f);
  k_spmm2<true ><<<qgrid, TB, 0, stream>>>(ptr_f, col_f, val_f, ptr_b, col_b, val_b,
                                           x1, x3, x2, x4, x0, xtail,
                                           1, 3, 2, 4, 0, N, 2.f, -1.f);
  // gates GEMM: writes ub (by=1) and x5 = [x_in, r*hx] in level-0 layout (by=0)
  k_gemm<64, 0><<<dim3(gx64, 2), TB, 0, stream>>>(
      xall, xtail, WtG, bg, hidden, inputs, x5, xtail, ub,
      nullptr, nullptr, nullptr, N, BN);

  // ---- candidate gconv (level 0 = x5) ----
  k_spmm2<false><<<qgrid, TB, 0, stream>>>(ptr_f, col_f, val_f, ptr_b, col_b, val_b,
                                           x5, x5, x1, x3, x5, xtail,
                                           8, 8, 9, 11, 8, N, 1.f, 0.f);
  k_spmm2<true ><<<qgrid, TB, 0, stream>>>(ptr_f, col_f, val_f, ptr_b, col_b, val_b,
                                           x1, x3, x2, x4, x5, xtail,
                                           9, 11, 10, 12, 8, N, 2.f, -1.f);
  k_gemm<32, 1><<<dim3(gx32, 1), TB, 0, stream>>>(
      xall, xtail, WtC, bc, hidden, nullptr, nullptr, nullptr, ub,
      out_h, out_y, Wpj, N, BN);
}

// Round 11
// 328.858 us; speedup vs baseline: 1.1383x; 1.1383x over previous
//
#include <hip/hip_runtime.h>
#include <cstdint>
#include <cstddef>

#define BATCH  4
#define RUNITS 128
#define MM     5
#define SEG    128            // ushorts per b-segment (c 0..127)
#define US     512            // ushorts per node row-level (1024 B)
#define MS     576            // fp8 mirror row stride in bytes (512 payload + 4 tails + pad)
#define KB     672            // GEMM K: 20 steps (m*128+c) + 1 tail step

typedef unsigned int  uint32;
typedef unsigned char uchar;
typedef unsigned short ushort16;
typedef __attribute__((ext_vector_type(8))) short short8;
typedef __attribute__((ext_vector_type(4))) float f32x4;
typedef __attribute__((ext_vector_type(2))) float f32x2;

__device__ inline float bflo(uint32 u){ return __uint_as_float(u << 16); }
__device__ inline float bfhi(uint32 u){ return __uint_as_float(u & 0xFFFF0000u); }
__device__ inline ushort16 f2bf(float f){
  uint32 u = __float_as_uint(f);
  return (ushort16)((u + 0x7FFFu + ((u >> 16) & 1u)) >> 16);
}
__device__ inline float bf2f(ushort16 v){ return __uint_as_float(((uint32)v) << 16); }
__device__ inline int sw4(int r){ return (r ^ (r >> 2)) & 3; }

__device__ inline uint32 pk4f8(float a, float b, float c, float d){
  uint32 w = __builtin_amdgcn_cvt_pk_fp8_f32(a, b, 0u, false);
  w = __builtin_amdgcn_cvt_pk_fp8_f32(c, d, w, true);
  return w;
}
__device__ inline uchar f8(float a){
  return (uchar)(__builtin_amdgcn_cvt_pk_fp8_f32(a, 0.f, 0u, false) & 0xFFu);
}

// ---------------- graph prep ----------------

__global__ void k_zero_i(int* p, int n) {
  int i = blockIdx.x*blockDim.x + threadIdx.x;
  if (i < n) p[i] = 0;
}

__global__ void k_deg_cnt(const int* __restrict__ src, const int* __restrict__ dst,
                          const float* __restrict__ w, int E,
                          float* deg_out, float* deg_in, int* cnt_f, int* cnt_b) {
  int e = blockIdx.x*blockDim.x + threadIdx.x;
  if (e >= E) return;
  int s = src[e], d = dst[e]; float we = w[e];
  atomicAdd(&deg_out[s], we);
  atomicAdd(&deg_in[d], we);
  atomicAdd(&cnt_f[s], 1);
  atomicAdd(&cnt_b[d], 1);
}

__global__ __launch_bounds__(256) void k_scansum(
    const int* __restrict__ cnt_f, const int* __restrict__ cnt_b, int* bsum, int n) {
  const int* cnt = blockIdx.y ? cnt_b : cnt_f;
  int tid = threadIdx.x, lane = tid & 63, wv = tid >> 6;
  int i = blockIdx.x*256 + tid;
  int v = (i < n) ? cnt[i] : 0;
  #pragma unroll
  for (int d = 32; d > 0; d >>= 1) v += __shfl_down(v, d);
  __shared__ int sm[4];
  if (lane == 0) sm[wv] = v;
  __syncthreads();
  if (tid == 0) bsum[blockIdx.y*40 + blockIdx.x] = sm[0]+sm[1]+sm[2]+sm[3];
}

__global__ __launch_bounds__(64) void k_scanmid(
    const int* bsum, int* bofs, int* ptrF, int* ptrB, int n, int nb) {
  int lane = threadIdx.x;
  for (int a = 0; a < 2; ++a) {
    int v = (lane < nb) ? bsum[a*nb + lane] : 0;
    int x = v;
    #pragma unroll
    for (int d = 1; d < 64; d <<= 1) { int t = __shfl_up(x, d); if (lane >= d) x += t; }
    if (lane < nb) bofs[a*nb + lane] = x - v;
    if (lane == nb - 1) { if (a) ptrB[n] = x; else ptrF[n] = x; }
  }
}

__global__ __launch_bounds__(256) void k_scanapply(
    const int* __restrict__ cnt_f, const int* __restrict__ cnt_b, const int* __restrict__ bofs,
    int* ptrF, int* curF, int* ptrB, int* curB, int n) {
  int a = blockIdx.y;
  const int* cnt = a ? cnt_b : cnt_f;
  int* ptr = a ? ptrB : ptrF;
  int* cur = a ? curB : curF;
  int tid = threadIdx.x, lane = tid & 63, wv = tid >> 6;
  int i = blockIdx.x*256 + tid;
  int v = (i < n) ? cnt[i] : 0;
  int x = v;
  #pragma unroll
  for (int d = 1; d < 64; d <<= 1) { int t = __shfl_up(x, d); if (lane >= d) x += t; }
  __shared__ int ws[4];
  __shared__ int wo[4];
  if (lane == 63) ws[wv] = x;
  __syncthreads();
  if (tid == 0) { int s = 0; for (int k = 0; k < 4; ++k) { wo[k] = s; s += ws[k]; } }
  __syncthreads();
  int excl = x - v + wo[wv] + bofs[a*40 + blockIdx.x];
  if (i < n) { ptr[i] = excl; cur[i] = excl; }
}

__global__ void k_fill(const int* __restrict__ src, const int* __restrict__ dst,
                       const float* __restrict__ w, int E,
                       const float* __restrict__ deg_out, const float* __restrict__ deg_in,
                       int* cur_f, int* cur_b,
                       int* col_f, float* val_f, int* col_b, float* val_b) {
  int e = blockIdx.x*blockDim.x + threadIdx.x;
  if (e >= E) return;
  int s = src[e], d = dst[e]; float we = w[e];
  int pf = atomicAdd(&cur_f[s], 1);
  col_f[pf] = d; val_f[pf] = we / deg_out[s];
  int pb = atomicAdd(&cur_b[d], 1);
  col_b[pb] = s; val_b[pb] = we / deg_in[d];
}

// ---------------- weight pack ----------------

__global__ void k_packw(const float* __restrict__ W, ushort16* __restrict__ Bt, int ncol) {
  int idx = blockIdx.x*blockDim.x + threadIdx.x;
  int total = ncol * KB;
  if (idx >= total) return;
  int o = idx / KB, k = idx - o*KB;
  float v = 0.f;
  if (k < 640) {
    int m = k >> 7, c = k & 127;
    v = W[(size_t)(c*MM + m)*ncol + o];
  } else if (k < 645) {
    v = W[(size_t)k*ncol + o];
  }
  Bt[idx] = f2bf(v);
}

// ---------------- build x0: bf16 level0 + fp8 mirror + tails ----------------
// xtail: [n][b][16 slots] bf16; mirror m0: [n][4 segs x 128 B + tails at 512..515]

__global__ __launch_bounds__(256) void k_build_x0(
    const float* __restrict__ inp, const float* __restrict__ hf,
    ushort16* __restrict__ x0, ushort16* __restrict__ xtail,
    uchar* __restrict__ m0, int N) {
  int wv = threadIdx.x >> 6, lane = threadIdx.x & 63;
  int n = blockIdx.x*4 + wv;
  if (n >= N) return;
  int b = lane >> 4, ch = lane & 15;
  size_t r = (size_t)b*N + n;
  size_t hbase = r*RUNITS;
  float fv[8];
  if (ch == 0) {
    fv[0] = inp[r];
    #pragma unroll
    for (int s = 1; s < 8; ++s) fv[s] = hf[hbase + s - 1];
  } else {
    int c0 = ch*8 - 1;
    #pragma unroll
    for (int s = 0; s < 8; ++s) fv[s] = hf[hbase + c0 + s];
  }
  short8 pk;
  #pragma unroll
  for (int s = 0; s < 8; ++s) pk[s] = (short)f2bf(fv[s]);
  *(short8*)&x0[(size_t)n*US + b*SEG + ch*8] = pk;
  uint2 mv;
  mv.x = pk4f8(fv[0], fv[1], fv[2], fv[3]);
  mv.y = pk4f8(fv[4], fv[5], fv[6], fv[7]);
  *(uint2*)(m0 + (size_t)n*MS + b*128 + ch*8) = mv;
  if (ch == 15) {
    float h127 = hf[hbase + 127];
    xtail[((size_t)n*4 + b)*16 + 0] = f2bf(h127);
    m0[(size_t)n*MS + 512 + b] = f8(h127);
  }
}

// ---------------- full-wave dual SPMM over fp8 mirrors ----------------
// wave per node; lane l gathers 8 fp8 = bytes [8l,8l+8); lanes 0..3 gather tail byte.
// Writes bf16 level (for GEMM) and, if WM, the fp8 mirror (for next gather).

template<bool HY, bool WM>
__global__ __launch_bounds__(256) void k_spmm2(
    const int* __restrict__ ptrF, const int* __restrict__ colF, const float* __restrict__ valF,
    const int* __restrict__ ptrB, const int* __restrict__ colB, const float* __restrict__ valB,
    const uchar* __restrict__ minF, const uchar* __restrict__ minB,
    ushort16* __restrict__ xoutF, ushort16* __restrict__ xoutB,
    uchar* __restrict__ moutF, uchar* __restrict__ moutB,
    const ushort16* __restrict__ Y0, ushort16* __restrict__ xtail,
    int toutF, int toutB, int tz,
    int N, int sgrid, float alpha, float beta) {
  int bid = blockIdx.x;
  bool jb = bid >= sgrid;
  const int* ptr = jb ? ptrB : ptrF;
  const int* col = jb ? colB : colF;
  const float* val = jb ? valB : valF;
  const uchar* M = jb ? minB : minF;
  ushort16* out = jb ? xoutB : xoutF;
  uchar* mout = jb ? moutB : moutF;
  int tout = jb ? toutB : toutF;
  int wv = threadIdx.x >> 6, lane = threadIdx.x & 63;
  int n = (bid - (jb ? sgrid : 0))*4 + wv;
  if (n >= N) return;
  int s = ptr[n], e = ptr[n+1];
  bool tq = lane < 4;
  float a[8] = {0.f,0.f,0.f,0.f,0.f,0.f,0.f,0.f};
  float at = 0.f;
  #pragma unroll 4
  for (int i = s; i < e; ++i) {
    int cl = col[i]; float v = val[i];
    const uchar* Mr = M + (size_t)cl*MS;
    uint2 u = *(const uint2*)(Mr + lane*8);
    f32x2 p0 = __builtin_amdgcn_cvt_pk_f32_fp8(u.x, false);
    f32x2 p1 = __builtin_amdgcn_cvt_pk_f32_fp8(u.x, true);
    f32x2 p2 = __builtin_amdgcn_cvt_pk_f32_fp8(u.y, false);
    f32x2 p3 = __builtin_amdgcn_cvt_pk_f32_fp8(u.y, true);
    a[0] += v*p0.x; a[1] += v*p0.y;
    a[2] += v*p1.x; a[3] += v*p1.y;
    a[4] += v*p2.x; a[5] += v*p2.y;
    a[6] += v*p3.x; a[7] += v*p3.y;
    if (tq) {
      uint32 tb = Mr[512 + lane];
      at += v * __builtin_amdgcn_cvt_f32_fp8(tb, 0);
    }
  }
  size_t ob = (size_t)n*US + lane*8;
  float r[8];
  if (HY) {
    uint4 y = *(const uint4*)(Y0 + ob);
    r[0] = alpha*a[0] + beta*bflo(y.x); r[1] = alpha*a[1] + beta*bfhi(y.x);
    r[2] = alpha*a[2] + beta*bflo(y.y); r[3] = alpha*a[3] + beta*bfhi(y.y);
    r[4] = alpha*a[4] + beta*bflo(y.z); r[5] = alpha*a[5] + beta*bfhi(y.z);
    r[6] = alpha*a[6] + beta*bflo(y.w); r[7] = alpha*a[7] + beta*bfhi(y.w);
  } else {
    #pragma unroll
    for (int k = 0; k < 8; ++k) r[k] = alpha*a[k];
  }
  short8 pk;
  #pragma unroll
  for (int k = 0; k < 8; ++k) pk[k] = (short)f2bf(r[k]);
  *(short8*)&out[ob] = pk;
  if (WM) {
    uint2 mv;
    mv.x = pk4f8(r[0], r[1], r[2], r[3]);
    mv.y = pk4f8(r[4], r[5], r[6], r[7]);
    *(uint2*)(mout + (size_t)n*MS + lane*8) = mv;
  }
  if (tq) {
    float rt = alpha*at;
    if (HY) rt += beta * bf2f(xtail[((size_t)n*4 + lane)*16 + tz]);
    xtail[((size_t)n*4 + lane)*16 + tout] = f2bf(rt);
    if (WM) mout[(size_t)n*MS + 512 + lane] = f8(rt);
  }
}

// ---------------- unified MFMA GEMM ----------------
// MODE 0 (gates, grid.y=2): sigmoid; by=0 -> r*hx into x5 (bf16) + m0 (fp8) + tails;
//   by=1 -> ub. MODE 1 (cand, level0 = x5): tanh + GRU + fused projection.

template<int TM, int MODE>
__global__ __launch_bounds__(256, 5) void k_gemm(
    const ushort16* __restrict__ xall, const ushort16* __restrict__ xtail,
    const ushort16* __restrict__ Bt, const float* __restrict__ bias,
    const float* __restrict__ hx, const float* __restrict__ inp,
    ushort16* __restrict__ x5w, ushort16* __restrict__ xtw,
    uchar* __restrict__ x5m, ushort16* __restrict__ ub,
    float* __restrict__ outh, float* __restrict__ outy,
    const float* __restrict__ wpj, int N, int BN) {
  constexpr int NI = TM / 32;
  __shared__ __align__(16) ushort16 As[2][TM*32];
  __shared__ __align__(16) ushort16 Bs[2][128*32];
  int tid = threadIdx.x, lane = tid & 63, wv = tid >> 6;
  int wm = wv >> 1, wn = wv & 1;
  int fr = lane & 15, g = lane >> 4;
  int R0 = blockIdx.x*TM, by = blockIdx.y;
  const size_t mstride = (size_t)N*US;
  const size_t l0off = (MODE == 1) ? (size_t)5*mstride : 0;

  int r = tid >> 2, p = tid & 3;
  bool aact = (TM == 64) || (tid < TM*4);
  int sa = p ^ sw4(r);
  int gr = R0 + r; if (gr >= BN) gr = BN - 1;
  int bA = gr / N, nA = gr - bA*N;
  const ushort16* aBase = xall + (size_t)nA*US + bA*SEG;
  const ushort16* tBase = xtail + ((size_t)nA*4 + bA)*16 + (MODE == 1 ? 8 : 0);
  int aofs = r*32 + (p << 3);

  int cB = tid >> 1, u = tid & 1;
  int p0 = 2*u, p1 = 2*u + 1;
  int sb0 = p0 ^ sw4(cB), sb1 = p1 ^ sw4(cB);
  const ushort16* bBase = Bt + (size_t)(by*128 + cB)*KB;
  int bofs0 = cB*32 + (p0 << 3), bofs1 = cB*32 + (p1 << 3);

  f32x4 acc[NI][4];
  #pragma unroll
  for (int i = 0; i < NI; ++i)
    #pragma unroll
    for (int j = 0; j < 4; ++j) acc[i][j] = (f32x4){0.f,0.f,0.f,0.f};

  uint4 ra, rb0, rb1;
  if (aact) ra = *(const uint4*)(aBase + l0off + sa*8);
  rb0 = *(const uint4*)(bBase + sb0*8);
  rb1 = *(const uint4*)(bBase + sb1*8);

  int buf = 0;
  for (int s = 0; s < 21; ++s) {
    if (aact) *(uint4*)&As[buf][aofs] = ra;
    *(uint4*)&Bs[buf][bofs0] = rb0;
    *(uint4*)&Bs[buf][bofs1] = rb1;
    __syncthreads();
    if (s < 20) {
      int s1 = s + 1;
      if (aact) {
        if (s1 < 20) {
          int qk = 4*s1 + sa;
          int m = qk >> 4;
          size_t mo = (m == 0) ? l0off : (size_t)m*mstride;
          ra = *(const uint4*)(aBase + mo + (qk & 15)*8);
        } else if (sa == 0) {
          ra = *(const uint4*)tBase;   // 5 real slots; pads/stale killed by B zeros
        }
      }
      rb0 = *(const uint4*)(bBase + (4*s1 + sb0)*8);
      rb1 = *(const uint4*)(bBase + (4*s1 + sb1)*8);
    }
    short8 af[NI], bfv[4];
    #pragma unroll
    for (int i = 0; i < NI; ++i) {
      int rr = wm*(NI*16) + i*16 + fr;
      af[i] = *(const short8*)&As[buf][rr*32 + ((g ^ sw4(rr)) << 3)];
    }
    #pragma unroll
    for (int j = 0; j < 4; ++j) {
      int cc = wn*64 + j*16 + fr;
      bfv[j] = *(const short8*)&Bs[buf][cc*32 + ((g ^ sw4(cc)) << 3)];
    }
    #pragma unroll
    for (int i = 0; i < NI; ++i)
      #pragma unroll
      for (int j = 0; j < 4; ++j)
        acc[i][j] = __builtin_amdgcn_mfma_f32_16x16x32_bf16(af[i], bfv[j], acc[i][j], 0, 0, 0);
    buf ^= 1;
  }

  #pragma unroll
  for (int i = 0; i < NI; ++i) {
    #pragma unroll
    for (int q2 = 0; q2 < 4; ++q2) {
      int row = R0 + wm*(NI*16) + i*16 + g*4 + q2;
      bool rok = row < BN;
      if (MODE == 0) {
        if (!rok) continue;
        int b2 = row / N, n2 = row - b2*N;
        #pragma unroll
        for (int j = 0; j < 4; ++j) {
          int o = wn*64 + j*16 + fr;
          float gv = acc[i][j][q2] + bias[by*128 + o];
          float sg = 1.f/(1.f + expf(-gv));
          if (by == 0) {
            float rv = sg * hx[(size_t)row*RUNITS + o];
            if (o < 127) {
              x5w[(size_t)n2*US + b2*SEG + o + 1] = f2bf(rv);
              x5m[(size_t)n2*MS + b2*128 + o + 1] = f8(rv);
            } else {
              xtw[((size_t)n2*4 + b2)*16 + 8] = f2bf(rv);
              x5m[(size_t)n2*MS + 512 + b2] = f8(rv);
            }
            if (o == 0) {
              float iv = inp[row];
              x5w[(size_t)n2*US + b2*SEG] = f2bf(iv);
              x5m[(size_t)n2*MS + b2*128] = f8(iv);
            }
          } else {
            ub[(size_t)row*RUNITS + o] = f2bf(sg);
          }
        }
      } else {
        float pj = 0.f;
        #pragma unroll
        for (int j = 0; j < 4; ++j) {
          int o = wn*64 + j*16 + fr;
          float gv = acc[i][j][q2] + bias[o];
          float cv = tanhf(gv);
          if (rok) {
            float uu = bf2f(ub[(size_t)row*RUNITS + o]);
            float hh = hx[(size_t)row*RUNITS + o];
            float nh = uu*hh + (1.f - uu)*cv;
            outh[(size_t)row*RUNITS + o] = nh;
            pj += nh * wpj[o];
          }
        }
        #pragma unroll
        for (int d = 1; d < 16; d <<= 1) pj += __shfl_xor(pj, d);
        if (rok && fr == 0) atomicAdd(&outy[row], pj);
      }
    }
  }
}

__global__ void k_inity(float* y, const float* bp, int n) {
  int i = blockIdx.x*blockDim.x + threadIdx.x;
  if (i < n) y[i] = bp[0];
}

// ---------------- launcher ----------------

extern "C" void kernel_launch(void* const* d_in, const int* in_sizes, int n_in,
                              void* d_out, int out_size, void* d_ws, size_t ws_size,
                              hipStream_t stream) {
  const float* inputs = (const float*)d_in[0];
  const float* hidden = (const float*)d_in[1];
  const int*   esrc   = (const int*)d_in[2];
  const int*   edst   = (const int*)d_in[3];
  const float* ew     = (const float*)d_in[4];
  const float* Wg     = (const float*)d_in[5];
  const float* bg     = (const float*)d_in[6];
  const float* Wc     = (const float*)d_in[7];
  const float* bc     = (const float*)d_in[8];
  const float* Wpj    = (const float*)d_in[9];
  const float* bpj    = (const float*)d_in[10];

  const int N  = in_sizes[0] / BATCH;
  const int E  = in_sizes[2];
  const int BN = BATCH * N;

  char* p = (char*)d_ws;
  auto alloc = [&](size_t bytes) -> void* {
    void* r = (void*)p;
    p += (bytes + 255) & ~(size_t)255;
    return r;
  };

  float* deg_out = (float*)alloc((size_t)4*N*sizeof(float));
  float* deg_in  = deg_out + N;
  int*   cnt_f   = (int*)(deg_out + 2*(size_t)N);
  int*   cnt_b   = cnt_f + N;
  int*   ptr_f   = (int*)alloc((size_t)(N+1)*sizeof(int));
  int*   ptr_b   = (int*)alloc((size_t)(N+1)*sizeof(int));
  int*   cur_f   = (int*)alloc((size_t)N*sizeof(int));
  int*   cur_b   = (int*)alloc((size_t)N*sizeof(int));
  int*   col_f   = (int*)alloc((size_t)E*sizeof(int));
  int*   col_b   = (int*)alloc((size_t)E*sizeof(int));
  float* val_f   = (float*)alloc((size_t)E*sizeof(float));
  float* val_b   = (float*)alloc((size_t)E*sizeof(float));
  int*   bsum    = (int*)alloc(80*sizeof(int));
  int*   bofs    = (int*)alloc(80*sizeof(int));
  ushort16* WtG  = (ushort16*)alloc((size_t)2*RUNITS*KB*sizeof(ushort16));
  ushort16* WtC  = (ushort16*)alloc((size_t)RUNITS*KB*sizeof(ushort16));
  ushort16* xall = (ushort16*)alloc((size_t)6*N*US*sizeof(ushort16));   // levels 0..4 + x5
  ushort16* xtail= (ushort16*)alloc((size_t)N*4*16*sizeof(ushort16));
  uchar* m0      = (uchar*)alloc((size_t)N*MS);
  uchar* m1      = (uchar*)alloc((size_t)N*MS);
  uchar* m3      = (uchar*)alloc((size_t)N*MS);
  ushort16* ub   = (ushort16*)alloc((size_t)BN*RUNITS*sizeof(ushort16));

  float* out_y = (float*)d_out;
  float* out_h = out_y + BN;

  ushort16* x0 = xall;
  ushort16* x1 = xall + (size_t)1*N*US;
  ushort16* x2 = xall + (size_t)2*N*US;
  ushort16* x3 = xall + (size_t)3*N*US;
  ushort16* x4 = xall + (size_t)4*N*US;
  ushort16* x5 = xall + (size_t)5*N*US;

  const int TB = 256;
  int nb = (N + 255)/256;
  k_zero_i<<<(4*N+TB-1)/TB, TB, 0, stream>>>((int*)deg_out, 4*N);
  k_deg_cnt<<<(E+TB-1)/TB, TB, 0, stream>>>(esrc, edst, ew, E, deg_out, deg_in, cnt_f, cnt_b);
  k_scansum<<<dim3(nb,2), TB, 0, stream>>>(cnt_f, cnt_b, bsum, N);
  k_scanmid<<<1, 64, 0, stream>>>(bsum, bofs, ptr_f, ptr_b, N, nb);
  k_scanapply<<<dim3(nb,2), TB, 0, stream>>>(cnt_f, cnt_b, bofs, ptr_f, cur_f, ptr_b, cur_b, N);
  k_fill<<<(E+TB-1)/TB, TB, 0, stream>>>(esrc, edst, ew, E, deg_out, deg_in,
                                         cur_f, cur_b, col_f, val_f, col_b, val_b);
  k_packw<<<(2*RUNITS*KB+TB-1)/TB, TB, 0, stream>>>(Wg, WtG, 2*RUNITS);
  k_packw<<<(RUNITS*KB+TB-1)/TB, TB, 0, stream>>>(Wc, WtC, RUNITS);
  k_inity<<<(BN+TB-1)/TB, TB, 0, stream>>>(out_y, bpj, BN);

  int sgrid = (N + 3) / 4;
  int gx64 = (BN + 63) / 64;
  int gx32 = (BN + 31) / 32;

  // ---- gates gconv ----
  k_build_x0<<<sgrid, TB, 0, stream>>>(inputs, hidden, x0, xtail, m0, N);
  k_spmm2<false, true><<<2*sgrid, TB, 0, stream>>>(
      ptr_f, col_f, val_f, ptr_b, col_b, val_b,
      m0, m0, x1, x3, m1, m3, x0, xtail,
      1, 3, 0, N, sgrid, 1.f, 0.f);
  k_spmm2<true, false><<<2*sgrid, TB, 0, stream>>>(
      ptr_f, col_f, val_f, ptr_b, col_b, val_b,
      m1, m3, x2, x4, nullptr, nullptr, x0, xtail,
      2, 4, 0, N, sgrid, 2.f, -1.f);
  // gates GEMM: ub (by=1); x5 = [x_in, r*hx] bf16 + m0 fp8 mirror (by=0)
  k_gemm<64, 0><<<dim3(gx64, 2), TB, 0, stream>>>(
      xall, xtail, WtG, bg, hidden, inputs, x5, xtail, m0, ub,
      nullptr, nullptr, nullptr, N, BN);

  // ---- candidate gconv (level 0 = x5, mirror m0) ----
  k_spmm2<false, true><<<2*sgrid, TB, 0, stream>>>(
      ptr_f, col_f, val_f, ptr_b, col_b, val_b,
      m0, m0, x1, x3, m1, m3, x5, xtail,
      9, 11, 8, N, sgrid, 1.f, 0.f);
  k_spmm2<true, false><<<2*sgrid, TB, 0, stream>>>(
      ptr_f, col_f, val_f, ptr_b, col_b, val_b,
      m1, m3, x2, x4, nullptr, nullptr, x5, xtail,
      10, 12, 8, N, sgrid, 2.f, -1.f);
  k_gemm<32, 1><<<dim3(gx32, 1), TB, 0, stream>>>(
      xall, xtail, WtC, bc, hidden, nullptr, nullptr, nullptr, nullptr, ub,
      out_h, out_y, Wpj, N, BN);
}

// Round 12
// 320.325 us; speedup vs baseline: 1.1686x; 1.0266x over previous
//
#include <hip/hip_runtime.h>
#include <cstdint>
#include <cstddef>

#define BATCH  4
#define RUNITS 128
#define MM     5
#define SEG    128            // ushorts per b-segment (c 0..127)
#define US     512            // ushorts per node row-level (1024 B)
#define MS     512            // fp8 mirror row stride in bytes (payload only)
#define KB     672            // GEMM K: 20 steps (m*128+c) + 1 tail step

typedef unsigned int  uint32;
typedef unsigned char uchar;
typedef unsigned short ushort16;
typedef __attribute__((ext_vector_type(8))) short short8;
typedef __attribute__((ext_vector_type(4))) float f32x4;
typedef __attribute__((ext_vector_type(2))) float f32x2;

__device__ inline float bflo(uint32 u){ return __uint_as_float(u << 16); }
__device__ inline float bfhi(uint32 u){ return __uint_as_float(u & 0xFFFF0000u); }
__device__ inline ushort16 f2bf(float f){
  uint32 u = __float_as_uint(f);
  return (ushort16)((u + 0x7FFFu + ((u >> 16) & 1u)) >> 16);
}
__device__ inline uint32 packbf(float a, float b){
  return (uint32)f2bf(a) | ((uint32)f2bf(b) << 16);
}
__device__ inline float bf2f(ushort16 v){ return __uint_as_float(((uint32)v) << 16); }
__device__ inline int sw4(int r){ return (r ^ (r >> 2)) & 3; }

__device__ inline uint32 pk4f8(float a, float b, float c, float d){
  uint32 w = __builtin_amdgcn_cvt_pk_fp8_f32(a, b, 0u, false);
  w = __builtin_amdgcn_cvt_pk_fp8_f32(c, d, w, true);
  return w;
}
__device__ inline uchar f8(float a){
  return (uchar)(__builtin_amdgcn_cvt_pk_fp8_f32(a, 0.f, 0u, false) & 0xFFu);
}
// 8 fp8 bytes -> uint4 of 8 bf16
__device__ inline uint4 f8x8_to_bf8(uint2 u8){
  f32x2 p0 = __builtin_amdgcn_cvt_pk_f32_fp8(u8.x, false);
  f32x2 p1 = __builtin_amdgcn_cvt_pk_f32_fp8(u8.x, true);
  f32x2 p2 = __builtin_amdgcn_cvt_pk_f32_fp8(u8.y, false);
  f32x2 p3 = __builtin_amdgcn_cvt_pk_f32_fp8(u8.y, true);
  uint4 r;
  r.x = packbf(p0.x, p0.y); r.y = packbf(p1.x, p1.y);
  r.z = packbf(p2.x, p2.y); r.w = packbf(p3.x, p3.y);
  return r;
}

// ---------------- graph prep ----------------

__global__ void k_zero_i(int* p, int n) {
  int i = blockIdx.x*blockDim.x + threadIdx.x;
  if (i < n) p[i] = 0;
}

__global__ void k_deg_cnt(const int* __restrict__ src, const int* __restrict__ dst,
                          const float* __restrict__ w, int E,
                          float* deg_out, float* deg_in, int* cnt_f, int* cnt_b) {
  int e = blockIdx.x*blockDim.x + threadIdx.x;
  if (e >= E) return;
  int s = src[e], d = dst[e]; float we = w[e];
  atomicAdd(&deg_out[s], we);
  atomicAdd(&deg_in[d], we);
  atomicAdd(&cnt_f[s], 1);
  atomicAdd(&cnt_b[d], 1);
}

__global__ __launch_bounds__(256) void k_scansum(
    const int* __restrict__ cnt_f, const int* __restrict__ cnt_b, int* bsum, int n) {
  const int* cnt = blockIdx.y ? cnt_b : cnt_f;
  int tid = threadIdx.x, lane = tid & 63, wv = tid >> 6;
  int i = blockIdx.x*256 + tid;
  int v = (i < n) ? cnt[i] : 0;
  #pragma unroll
  for (int d = 32; d > 0; d >>= 1) v += __shfl_down(v, d);
  __shared__ int sm[4];
  if (lane == 0) sm[wv] = v;
  __syncthreads();
  if (tid == 0) bsum[blockIdx.y*40 + blockIdx.x] = sm[0]+sm[1]+sm[2]+sm[3];
}

__global__ __launch_bounds__(64) void k_scanmid(
    const int* bsum, int* bofs, int* ptrF, int* ptrB, int n, int nb) {
  int lane = threadIdx.x;
  for (int a = 0; a < 2; ++a) {
    int v = (lane < nb) ? bsum[a*nb + lane] : 0;
    int x = v;
    #pragma unroll
    for (int d = 1; d < 64; d <<= 1) { int t = __shfl_up(x, d); if (lane >= d) x += t; }
    if (lane < nb) bofs[a*nb + lane] = x - v;
    if (lane == nb - 1) { if (a) ptrB[n] = x; else ptrF[n] = x; }
  }
}

__global__ __launch_bounds__(256) void k_scanapply(
    const int* __restrict__ cnt_f, const int* __restrict__ cnt_b, const int* __restrict__ bofs,
    int* ptrF, int* curF, int* ptrB, int* curB, int n) {
  int a = blockIdx.y;
  const int* cnt = a ? cnt_b : cnt_f;
  int* ptr = a ? ptrB : ptrF;
  int* cur = a ? curB : curF;
  int tid = threadIdx.x, lane = tid & 63, wv = tid >> 6;
  int i = blockIdx.x*256 + tid;
  int v = (i < n) ? cnt[i] : 0;
  int x = v;
  #pragma unroll
  for (int d = 1; d < 64; d <<= 1) { int t = __shfl_up(x, d); if (lane >= d) x += t; }
  __shared__ int ws[4];
  __shared__ int wo[4];
  if (lane == 63) ws[wv] = x;
  __syncthreads();
  if (tid == 0) { int s = 0; for (int k = 0; k < 4; ++k) { wo[k] = s; s += ws[k]; } }
  __syncthreads();
  int excl = x - v + wo[wv] + bofs[a*40 + blockIdx.x];
  if (i < n) { ptr[i] = excl; cur[i] = excl; }
}

__global__ void k_fill(const int* __restrict__ src, const int* __restrict__ dst,
                       const float* __restrict__ w, int E,
                       const float* __restrict__ deg_out, const float* __restrict__ deg_in,
                       int* cur_f, int* cur_b,
                       int* col_f, float* val_f, int* col_b, float* val_b) {
  int e = blockIdx.x*blockDim.x + threadIdx.x;
  if (e >= E) return;
  int s = src[e], d = dst[e]; float we = w[e];
  int pf = atomicAdd(&cur_f[s], 1);
  col_f[pf] = d; val_f[pf] = we / deg_out[s];
  int pb = atomicAdd(&cur_b[d], 1);
  col_b[pb] = s; val_b[pb] = we / deg_in[d];
}

// ---------------- weight pack (both matrices, one launch) ----------------

__global__ void k_packw2(const float* __restrict__ Wg, const float* __restrict__ Wc,
                         ushort16* __restrict__ WtG, ushort16* __restrict__ WtC) {
  int idx = blockIdx.x*blockDim.x + threadIdx.x;
  const int tg = 2*RUNITS*KB;
  const int tc = RUNITS*KB;
  if (idx >= tg + tc) return;
  const float* W; ushort16* Wt; int ncol;
  if (idx < tg) { W = Wg; Wt = WtG; ncol = 2*RUNITS; }
  else { idx -= tg; W = Wc; Wt = WtC; ncol = RUNITS; }
  int o = idx / KB, k = idx - o*KB;
  float v = 0.f;
  if (k < 640) {
    int m = k >> 7, c = k & 127;
    v = W[(size_t)(c*MM + m)*ncol + o];
  } else if (k < 645) {
    v = W[(size_t)k*ncol + o];
  }
  Wt[idx + (W == Wc ? 0 : 0)] = f2bf(v);   // idx already local to the selected matrix
}

// ---------------- build x0: fp8 mirror mA0 + tails (slot 0) ----------------
// xtail: [n][b][16 slots] bf16; tl8: [slot][b][N] fp8

__global__ __launch_bounds__(256) void k_build_x0(
    const float* __restrict__ inp, const float* __restrict__ hf,
    uchar* __restrict__ mA0, ushort16* __restrict__ xtail,
    uchar* __restrict__ tl8, int N) {
  int wv = threadIdx.x >> 6, lane = threadIdx.x & 63;
  int n = blockIdx.x*4 + wv;
  if (n >= N) return;
  int b = lane >> 4, ch = lane & 15;
  size_t r = (size_t)b*N + n;
  size_t hbase = r*RUNITS;
  float fv[8];
  if (ch == 0) {
    fv[0] = inp[r];
    #pragma unroll
    for (int s = 1; s < 8; ++s) fv[s] = hf[hbase + s - 1];
  } else {
    int c0 = ch*8 - 1;
    #pragma unroll
    for (int s = 0; s < 8; ++s) fv[s] = hf[hbase + c0 + s];
  }
  uint2 mv;
  mv.x = pk4f8(fv[0], fv[1], fv[2], fv[3]);
  mv.y = pk4f8(fv[4], fv[5], fv[6], fv[7]);
  *(uint2*)(mA0 + (size_t)n*MS + b*128 + ch*8) = mv;
  if (ch == 15) {
    float h127 = hf[hbase + 127];
    xtail[((size_t)n*4 + b)*16 + 0] = f2bf(h127);
    tl8[(size_t)(0*4 + b)*N + n] = f8(h127);
  }
}

// ---------------- full-wave dual SPMM over fp8 mirrors ----------------
// wave per node; lane l gathers 8 fp8 bytes (8 cold lines/row); tails from hot tl8.

template<bool HY, bool WM>
__global__ __launch_bounds__(256) void k_spmm2(
    const int* __restrict__ ptrF, const int* __restrict__ colF, const float* __restrict__ valF,
    const int* __restrict__ ptrB, const int* __restrict__ colB, const float* __restrict__ valB,
    const uchar* __restrict__ minF, const uchar* __restrict__ minB,
    ushort16* __restrict__ xoutF, ushort16* __restrict__ xoutB,
    uchar* __restrict__ moutF, uchar* __restrict__ moutB,
    const uchar* __restrict__ mY0, ushort16* __restrict__ xtail,
    uchar* __restrict__ tl8,
    int tinF, int tinB, int toutF, int toutB, int tz,
    int N, int sgrid, float alpha, float beta) {
  int bid = blockIdx.x;
  bool jb = bid >= sgrid;
  const int* ptr = jb ? ptrB : ptrF;
  const int* col = jb ? colB : colF;
  const float* val = jb ? valB : valF;
  const uchar* M = jb ? minB : minF;
  ushort16* out = jb ? xoutB : xoutF;
  uchar* mout = jb ? moutB : moutF;
  int tin = jb ? tinB : tinF;
  int tout = jb ? toutB : toutF;
  int wv = threadIdx.x >> 6, lane = threadIdx.x & 63;
  int n = (bid - (jb ? sgrid : 0))*4 + wv;
  if (n >= N) return;
  int s = ptr[n], e = ptr[n+1];
  bool tq = lane < 4;
  const uchar* tlin = tl8 + (size_t)(tin*4 + lane)*N;   // valid for lane<4 use
  float a[8] = {0.f,0.f,0.f,0.f,0.f,0.f,0.f,0.f};
  float at = 0.f;
  #pragma unroll 4
  for (int i = s; i < e; ++i) {
    int cl = col[i]; float v = val[i];
    uint2 u = *(const uint2*)(M + (size_t)cl*MS + lane*8);
    f32x2 p0 = __builtin_amdgcn_cvt_pk_f32_fp8(u.x, false);
    f32x2 p1 = __builtin_amdgcn_cvt_pk_f32_fp8(u.x, true);
    f32x2 p2 = __builtin_amdgcn_cvt_pk_f32_fp8(u.y, false);
    f32x2 p3 = __builtin_amdgcn_cvt_pk_f32_fp8(u.y, true);
    a[0] += v*p0.x; a[1] += v*p0.y;
    a[2] += v*p1.x; a[3] += v*p1.y;
    a[4] += v*p2.x; a[5] += v*p2.y;
    a[6] += v*p3.x; a[7] += v*p3.y;
    if (tq) {
      uint32 tb = tlin[cl];
      at += v * __builtin_amdgcn_cvt_f32_fp8(tb, 0);
    }
  }
  size_t ob = (size_t)n*US + lane*8;
  float r[8];
  if (HY) {
    uint2 y8 = *(const uint2*)(mY0 + (size_t)n*MS + lane*8);
    f32x2 y0 = __builtin_amdgcn_cvt_pk_f32_fp8(y8.x, false);
    f32x2 y1 = __builtin_amdgcn_cvt_pk_f32_fp8(y8.x, true);
    f32x2 y2 = __builtin_amdgcn_cvt_pk_f32_fp8(y8.y, false);
    f32x2 y3 = __builtin_amdgcn_cvt_pk_f32_fp8(y8.y, true);
    r[0] = alpha*a[0] + beta*y0.x; r[1] = alpha*a[1] + beta*y0.y;
    r[2] = alpha*a[2] + beta*y1.x; r[3] = alpha*a[3] + beta*y1.y;
    r[4] = alpha*a[4] + beta*y2.x; r[5] = alpha*a[5] + beta*y2.y;
    r[6] = alpha*a[6] + beta*y3.x; r[7] = alpha*a[7] + beta*y3.y;
  } else {
    #pragma unroll
    for (int k = 0; k < 8; ++k) r[k] = alpha*a[k];
  }
  short8 pk;
  #pragma unroll
  for (int k = 0; k < 8; ++k) pk[k] = (short)f2bf(r[k]);
  *(short8*)&out[ob] = pk;
  if (WM) {
    uint2 mv;
    mv.x = pk4f8(r[0], r[1], r[2], r[3]);
    mv.y = pk4f8(r[4], r[5], r[6], r[7]);
    *(uint2*)(mout + (size_t)n*MS + lane*8) = mv;
  }
  if (tq) {
    float rt = alpha*at;
    if (HY) rt += beta * bf2f(xtail[((size_t)n*4 + lane)*16 + tz]);
    xtail[((size_t)n*4 + lane)*16 + tout] = f2bf(rt);
    if (WM) tl8[(size_t)(tout*4 + lane)*N + n] = f8(rt);
  }
}

// ---------------- unified MFMA GEMM ----------------
// A level m=0 staged from fp8 mirror mA (converted in staging); m=1..4 from bf16 xall.
// MODE 0 (gates, grid.y=2): sigmoid; by=0 -> r*hx into mB0 (fp8) + tails; by=1 -> ub.
// MODE 1 (cand): tanh + GRU combine + fused projection (LDS-reduced, +bias).

template<int TM, int MODE>
__global__ __launch_bounds__(256, 5) void k_gemm(
    const ushort16* __restrict__ xall, const ushort16* __restrict__ xtail,
    const uchar* __restrict__ mA,
    const ushort16* __restrict__ Bt, const float* __restrict__ bias,
    const float* __restrict__ hx, const float* __restrict__ inp,
    uchar* __restrict__ mB0, ushort16* __restrict__ xtw, uchar* __restrict__ tl8,
    ushort16* __restrict__ ub, float* __restrict__ outh,
    float* __restrict__ outy, const float* __restrict__ wpj,
    const float* __restrict__ bpj, int N, int BN) {
  constexpr int NI = TM / 32;
  __shared__ __align__(16) ushort16 As[2][TM*32];
  __shared__ __align__(16) ushort16 Bs[2][128*32];
  __shared__ float pjl[TM][2];
  int tid = threadIdx.x, lane = tid & 63, wv = tid >> 6;
  int wm = wv >> 1, wn = wv & 1;
  int fr = lane & 15, g = lane >> 4;
  int R0 = blockIdx.x*TM, by = blockIdx.y;
  const size_t mstride = (size_t)N*US;

  int r = tid >> 2, p = tid & 3;
  bool aact = (TM == 64) || (tid < TM*4);
  int sa = p ^ sw4(r);
  int gr = R0 + r; if (gr >= BN) gr = BN - 1;
  int bA = gr / N, nA = gr - bA*N;
  const ushort16* aBase = xall + (size_t)nA*US + bA*SEG;
  const uchar* a0Base = mA + (size_t)nA*MS + bA*128;
  const ushort16* tBase = xtail + ((size_t)nA*4 + bA)*16 + (MODE == 1 ? 8 : 0);
  int aofs = r*32 + (p << 3);

  // B staging: balanced positions p0 = 2u + ((cB>>1)&1), p1 = p0^1
  int cB = tid >> 1, u = tid & 1;
  int p0 = 2*u + ((cB >> 1) & 1);
  int p1 = p0 ^ 1;
  int sb0 = p0 ^ sw4(cB), sb1 = p1 ^ sw4(cB);
  const ushort16* bBase = Bt + (size_t)(by*128 + cB)*KB;
  int bofs0 = cB*32 + (p0 << 3), bofs1 = cB*32 + (p1 << 3);

  f32x4 acc[NI][4];
  #pragma unroll
  for (int i = 0; i < NI; ++i)
    #pragma unroll
    for (int j = 0; j < 4; ++j) acc[i][j] = (f32x4){0.f,0.f,0.f,0.f};

  uint4 ra, rb0, rb1;
  if (aact) ra = f8x8_to_bf8(*(const uint2*)(a0Base + sa*8));   // s=0: m=0
  rb0 = *(const uint4*)(bBase + sb0*8);
  rb1 = *(const uint4*)(bBase + sb1*8);

  int buf = 0;
  for (int s = 0; s < 21; ++s) {
    if (aact) *(uint4*)&As[buf][aofs] = ra;
    *(uint4*)&Bs[buf][bofs0] = rb0;
    *(uint4*)&Bs[buf][bofs1] = rb1;
    __syncthreads();
    if (s < 20) {
      int s1 = s + 1;
      if (aact) {
        if (s1 < 20) {
          int m = s1 >> 2;                 // wave-uniform
          int ch = (4*s1 + sa) & 15;
          if (m == 0) ra = f8x8_to_bf8(*(const uint2*)(a0Base + ch*8));
          else        ra = *(const uint4*)(aBase + (size_t)m*mstride + ch*8);
        } else if (sa == 0) {
          ra = *(const uint4*)tBase;       // tail: 5 real slots; rest killed by B zeros
        }
      }
      rb0 = *(const uint4*)(bBase + (4*s1 + sb0)*8);
      rb1 = *(const uint4*)(bBase + (4*s1 + sb1)*8);
    }
    short8 af[NI], bfv[4];
    #pragma unroll
    for (int i = 0; i < NI; ++i) {
      int rr = wm*(NI*16) + i*16 + fr;
      af[i] = *(const short8*)&As[buf][rr*32 + ((g ^ sw4(rr)) << 3)];
    }
    #pragma unroll
    for (int j = 0; j < 4; ++j) {
      int cc = wn*64 + j*16 + fr;
      bfv[j] = *(const short8*)&Bs[buf][cc*32 + ((g ^ sw4(cc)) << 3)];
    }
    #pragma unroll
    for (int i = 0; i < NI; ++i)
      #pragma unroll
      for (int j = 0; j < 4; ++j)
        acc[i][j] = __builtin_amdgcn_mfma_f32_16x16x32_bf16(af[i], bfv[j], acc[i][j], 0, 0, 0);
    buf ^= 1;
  }

  #pragma unroll
  for (int i = 0; i < NI; ++i) {
    #pragma unroll
    for (int q2 = 0; q2 < 4; ++q2) {
      int row = R0 + wm*(NI*16) + i*16 + g*4 + q2;
      bool rok = row < BN;
      if (MODE == 0) {
        if (!rok) continue;
        int b2 = row / N, n2 = row - b2*N;
        #pragma unroll
        for (int j = 0; j < 4; ++j) {
          int o = wn*64 + j*16 + fr;
          float gv = acc[i][j][q2] + bias[by*128 + o];
          float sg = 1.f/(1.f + expf(-gv));
          if (by == 0) {
            float rv = sg * hx[(size_t)row*RUNITS + o];
            if (o < 127) {
              mB0[(size_t)n2*MS + b2*128 + o + 1] = f8(rv);
            } else {
              xtw[((size_t)n2*4 + b2)*16 + 8] = f2bf(rv);
              tl8[(size_t)(8*4 + b2)*N + n2] = f8(rv);
            }
            if (o == 0) mB0[(size_t)n2*MS + b2*128] = f8(inp[row]);
          } else {
            ub[(size_t)row*RUNITS + o] = f2bf(sg);
          }
        }
      } else {
        float pj = 0.f;
        #pragma unroll
        for (int j = 0; j < 4; ++j) {
          int o = wn*64 + j*16 + fr;
          float gv = acc[i][j][q2] + bias[o];
          float cv = tanhf(gv);
          if (rok) {
            float uu = bf2f(ub[(size_t)row*RUNITS + o]);
            float hh = hx[(size_t)row*RUNITS + o];
            float nh = uu*hh + (1.f - uu)*cv;
            outh[(size_t)row*RUNITS + o] = nh;
            pj += nh * wpj[o];
          }
        }
        #pragma unroll
        for (int d = 1; d < 16; d <<= 1) pj += __shfl_xor(pj, d);
        if (rok && fr == 0) pjl[row - R0][wn] = pj;
      }
    }
  }
  if (MODE == 1) {
    __syncthreads();
    if (tid < TM) {
      int row = R0 + tid;
      if (row < BN) outy[row] = pjl[tid][0] + pjl[tid][1] + bpj[0];
    }
  }
}

// ---------------- launcher ----------------

extern "C" void kernel_launch(void* const* d_in, const int* in_sizes, int n_in,
                              void* d_out, int out_size, void* d_ws, size_t ws_size,
                              hipStream_t stream) {
  const float* inputs = (const float*)d_in[0];
  const float* hidden = (const float*)d_in[1];
  const int*   esrc   = (const int*)d_in[2];
  const int*   edst   = (const int*)d_in[3];
  const float* ew     = (const float*)d_in[4];
  const float* Wg     = (const float*)d_in[5];
  const float* bg     = (const float*)d_in[6];
  const float* Wc     = (const float*)d_in[7];
  const float* bc     = (const float*)d_in[8];
  const float* Wpj    = (const float*)d_in[9];
  const float* bpj    = (const float*)d_in[10];

  const int N  = in_sizes[0] / BATCH;
  const int E  = in_sizes[2];
  const int BN = BATCH * N;

  char* p = (char*)d_ws;
  auto alloc = [&](size_t bytes) -> void* {
    void* r = (void*)p;
    p += (bytes + 255) & ~(size_t)255;
    return r;
  };

  float* deg_out = (float*)alloc((size_t)4*N*sizeof(float));
  float* deg_in  = deg_out + N;
  int*   cnt_f   = (int*)(deg_out + 2*(size_t)N);
  int*   cnt_b   = cnt_f + N;
  int*   ptr_f   = (int*)alloc((size_t)(N+1)*sizeof(int));
  int*   ptr_b   = (int*)alloc((size_t)(N+1)*sizeof(int));
  int*   cur_f   = (int*)alloc((size_t)N*sizeof(int));
  int*   cur_b   = (int*)alloc((size_t)N*sizeof(int));
  int*   col_f   = (int*)alloc((size_t)E*sizeof(int));
  int*   col_b   = (int*)alloc((size_t)E*sizeof(int));
  float* val_f   = (float*)alloc((size_t)E*sizeof(float));
  float* val_b   = (float*)alloc((size_t)E*sizeof(float));
  int*   bsum    = (int*)alloc(80*sizeof(int));
  int*   bofs    = (int*)alloc(80*sizeof(int));
  ushort16* WtG  = (ushort16*)alloc((size_t)2*RUNITS*KB*sizeof(ushort16));
  ushort16* WtC  = (ushort16*)alloc((size_t)RUNITS*KB*sizeof(ushort16));
  ushort16* xall = (ushort16*)alloc((size_t)5*N*US*sizeof(ushort16));   // levels 1..4 used
  ushort16* xtail= (ushort16*)alloc((size_t)N*4*16*sizeof(ushort16));
  uchar* mA0     = (uchar*)alloc((size_t)N*MS);
  uchar* mB0     = (uchar*)alloc((size_t)N*MS);
  uchar* m1      = (uchar*)alloc((size_t)N*MS);
  uchar* m3      = (uchar*)alloc((size_t)N*MS);
  uchar* tl8     = (uchar*)alloc((size_t)16*4*N);
  ushort16* ub   = (ushort16*)alloc((size_t)BN*RUNITS*sizeof(ushort16));

  float* out_y = (float*)d_out;
  float* out_h = out_y + BN;

  ushort16* x1 = xall + (size_t)1*N*US;
  ushort16* x2 = xall + (size_t)2*N*US;
  ushort16* x3 = xall + (size_t)3*N*US;
  ushort16* x4 = xall + (size_t)4*N*US;

  const int TB = 256;
  int nb = (N + 255)/256;
  k_zero_i<<<(4*N+TB-1)/TB, TB, 0, stream>>>((int*)deg_out, 4*N);
  k_deg_cnt<<<(E+TB-1)/TB, TB, 0, stream>>>(esrc, edst, ew, E, deg_out, deg_in, cnt_f, cnt_b);
  k_scansum<<<dim3(nb,2), TB, 0, stream>>>(cnt_f, cnt_b, bsum, N);
  k_scanmid<<<1, 64, 0, stream>>>(bsum, bofs, ptr_f, ptr_b, N, nb);
  k_scanapply<<<dim3(nb,2), TB, 0, stream>>>(cnt_f, cnt_b, bofs, ptr_f, cur_f, ptr_b, cur_b, N);
  k_fill<<<(E+TB-1)/TB, TB, 0, stream>>>(esrc, edst, ew, E, deg_out, deg_in,
                                         cur_f, cur_b, col_f, val_f, col_b, val_b);
  {
    int tot = 3*RUNITS*KB;
    k_packw2<<<(tot+TB-1)/TB, TB, 0, stream>>>(Wg, Wc, WtG, WtC);
  }

  int sgrid = (N + 3) / 4;
  int gx64 = (BN + 63) / 64;
  int gx32 = (BN + 31) / 32;

  // ---- gates gconv ----
  k_build_x0<<<sgrid, TB, 0, stream>>>(inputs, hidden, mA0, xtail, tl8, N);
  k_spmm2<false, true><<<2*sgrid, TB, 0, stream>>>(
      ptr_f, col_f, val_f, ptr_b, col_b, val_b,
      mA0, mA0, x1, x3, m1, m3, mA0, xtail, tl8,
      0, 0, 1, 3, 0, N, sgrid, 1.f, 0.f);
  k_spmm2<true, false><<<2*sgrid, TB, 0, stream>>>(
      ptr_f, col_f, val_f, ptr_b, col_b, val_b,
      m1, m3, x2, x4, nullptr, nullptr, mA0, xtail, tl8,
      1, 3, 2, 4, 0, N, sgrid, 2.f, -1.f);
  // gates GEMM: ub (by=1); mB0 = fp8 [x_in, r*hx] + tails (by=0)
  k_gemm<64, 0><<<dim3(gx64, 2), TB, 0, stream>>>(
      xall, xtail, mA0, WtG, bg, hidden, inputs, mB0, xtail, tl8, ub,
      nullptr, nullptr, nullptr, nullptr, N, BN);

  // ---- candidate gconv (level 0 = mB0) ----
  k_spmm2<false, true><<<2*sgrid, TB, 0, stream>>>(
      ptr_f, col_f, val_f, ptr_b, col_b, val_b,
      mB0, mB0, x1, x3, m1, m3, mB0, xtail, tl8,
      8, 8, 9, 11, 8, N, sgrid, 1.f, 0.f);
  k_spmm2<true, false><<<2*sgrid, TB, 0, stream>>>(
      ptr_f, col_f, val_f, ptr_b, col_b, val_b,
      m1, m3, x2, x4, nullptr, nullptr, mB0, xtail, tl8,
      9, 11, 10, 12, 8, N, sgrid, 2.f, -1.f);
  k_gemm<32, 1><<<dim3(gx32, 1), TB, 0, stream>>>(
      xall, xtail, mB0, WtC, bc, hidden, nullptr, nullptr, nullptr, nullptr, ub,
      out_h, out_y, Wpj, bpj, N, BN);
}